// Round 6
// baseline (557.058 us; speedup 1.0000x reference)
//
#include <hip/hip_runtime.h>

#define HW 16384
#define NQ 300
#define NM 100
#define NB 8
#define NC 81
#define KCH 1024   // K split into 16 chunks
#define NKC 16
#define CTP 305    // odd pitch: bank-conflict-free for row and strided access

typedef __attribute__((ext_vector_type(8))) short frag8;
typedef __attribute__((ext_vector_type(4))) float float4v;
typedef __attribute__((ext_vector_type(4))) unsigned short ushort4v;

__device__ __forceinline__ unsigned short f2bf(float f) {
  union { float f; unsigned u; } c; c.f = f;
  unsigned r = c.u + 0x7FFFu + ((c.u >> 16) & 1u);
  return (unsigned short)(r >> 16);
}

// monotone (value, index) key: smaller float -> smaller key; ties -> smaller j
__device__ __forceinline__ unsigned long long packkey(float f, int j) {
  unsigned u = __float_as_uint(f);
  u = (u >> 31) ? ~u : (u | 0x80000000u);
  return ((unsigned long long)u << 32) | (unsigned)j;
}
__device__ __forceinline__ float unpackkey(unsigned long long k) {
  unsigned sb = (unsigned)(k >> 32);
  return __uint_as_float((sb >> 31) ? (sb ^ 0x80000000u) : ~sb);
}

// select slot w=j>>6 from a 5-reg array (uniform j), then broadcast from owner lane
#define GET5I(arr, j, res) { int _w = (j) >> 6; int _v = arr[0]; \
  if (_w == 1) _v = arr[1]; else if (_w == 2) _v = arr[2]; \
  else if (_w == 3) _v = arr[3]; else if (_w == 4) _v = arr[4]; \
  res = __shfl(_v, (j) & 63, 64); }
#define GET5F(arr, j, res) { int _w = (j) >> 6; float _v = arr[0]; \
  if (_w == 1) _v = arr[1]; else if (_w == 2) _v = arr[2]; \
  else if (_w == 3) _v = arr[3]; else if (_w == 4) _v = arr[4]; \
  res = __shfl(_v, (j) & 63, 64); }
#define SET5I(arr, w1, val) { switch (w1) { case 0: arr[0] = val; break; \
  case 1: arr[1] = val; break; case 2: arr[2] = val; break; \
  case 3: arr[3] = val; break; default: arr[4] = val; break; } }
#define SUB5F(arr, w1, val) { switch (w1) { case 0: arr[0] -= val; break; \
  case 1: arr[1] -= val; break; case 2: arr[2] -= val; break; \
  case 3: arr[3] -= val; break; default: arr[4] -= val; break; } }

// ---- prep: sigmoid(pred_masks)->bf16 + row sums; gt_masks->bf16 + row sums ----
__global__ __launch_bounds__(256) void prep_kernel(
    const float* __restrict__ pmask, const float* __restrict__ gmask,
    unsigned short* __restrict__ pm, unsigned short* __restrict__ gm,
    float* __restrict__ psum, float* __restrict__ gsum) {
  int row = blockIdx.x;            // 0..2399 = pm rows, 2400..3199 = gm rows
  int t = threadIdx.x;
  bool isP = row < NB * NQ;
  const float* srcf = isP ? (pmask + (size_t)row * HW)
                          : (gmask + (size_t)(row - NB * NQ) * HW);
  unsigned short* dst = isP ? (pm + (size_t)row * HW)
                            : (gm + (size_t)(row - NB * NQ) * HW);
  const float4v* src = (const float4v*)srcf;
  float s = 0.f;
  for (int i = t; i < HW / 4; i += 256) {
    float4v x = src[i];
    float y0, y1, y2, y3;
    if (isP) {
      y0 = 1.f / (1.f + __expf(-x.x));
      y1 = 1.f / (1.f + __expf(-x.y));
      y2 = 1.f / (1.f + __expf(-x.z));
      y3 = 1.f / (1.f + __expf(-x.w));
    } else { y0 = x.x; y1 = x.y; y2 = x.z; y3 = x.w; }
    s += (y0 + y1) + (y2 + y3);
    ushort4v o = { f2bf(y0), f2bf(y1), f2bf(y2), f2bf(y3) };
    *(ushort4v*)(dst + i * 4) = o;
  }
  for (int off = 32; off > 0; off >>= 1) s += __shfl_xor(s, off, 64);
  __shared__ float red[4];
  int wave = t >> 6, lane = t & 63;
  if (lane == 0) red[wave] = s;
  __syncthreads();
  if (t == 0) {
    float tot = (red[0] + red[1]) + (red[2] + red[3]);
    if (isP) psum[row] = tot; else gsum[row - NB * NQ] = tot;
  }
}

// ---- softmax over 81 classes, one wave per (b,q) row ----
__global__ __launch_bounds__(256) void softmax_kernel(
    const float* __restrict__ logits, float* __restrict__ probs) {
  int wave = threadIdx.x >> 6, lane = threadIdx.x & 63;
  int row = blockIdx.x * 4 + wave;          // < 2400 (grid=600)
  const float* in = logits + (size_t)row * NC;
  float x0 = (lane < NC) ? in[lane] : -1e30f;
  float x1 = (lane + 64 < NC) ? in[lane + 64] : -1e30f;
  float mx = fmaxf(x0, x1);
  for (int off = 32; off > 0; off >>= 1) mx = fmaxf(mx, __shfl_xor(mx, off, 64));
  float e0 = (lane < NC) ? __expf(x0 - mx) : 0.f;
  float e1 = (lane + 64 < NC) ? __expf(x1 - mx) : 0.f;
  float s = e0 + e1;
  for (int off = 32; off > 0; off >>= 1) s += __shfl_xor(s, off, 64);
  float inv = 1.f / s;
  if (lane < NC) probs[(size_t)row * NC + lane] = e0 * inv;
  if (lane + 64 < NC) probs[(size_t)row * NC + lane + 64] = e1 * inv;
}

// ---- bf16 MFMA batched GEMM: dot[b,q,m] accumulated via fp32 atomics ----
// XCD swizzle: b = blockIdx.x & 7 -> each batch's 3.3MB gt-mask set stays in
// one XCD's 4MB L2 across its 19 q-tiles x 16 k-chunks.
__global__ __launch_bounds__(64) void dot_kernel(
    const unsigned short* __restrict__ pm, const unsigned short* __restrict__ gm,
    float* __restrict__ dotv) {
  int blk = blockIdx.x;
  int b = blk & 7;
  int t = blk >> 3;                         // 0..303
  int qt = t % 19;
  int kc = t / 19;                          // 0..15
  int lane = threadIdx.x;
  int q0 = qt * 16;
  int row_a = q0 + (lane & 15);
  int ra = (row_a < NQ) ? row_a : NQ - 1;   // clamp; clamped rows never stored
  int koff = (lane >> 4) * 8;
  const unsigned short* pA = pm + ((size_t)b * NQ + ra) * HW + kc * KCH + koff;
  const unsigned short* pB0 = gm + (size_t)b * NM * HW + kc * KCH + koff;
  const unsigned short* pB[7];
#pragma unroll
  for (int mt = 0; mt < 7; ++mt) {
    int row_b = mt * 16 + (lane & 15);
    int rb = (row_b < NM) ? row_b : NM - 1;
    pB[mt] = pB0 + (size_t)rb * HW;
  }
  float4v acc[7];
#pragma unroll
  for (int mt = 0; mt < 7; ++mt) acc[mt] = (float4v){0.f, 0.f, 0.f, 0.f};
#pragma unroll 2
  for (int k = 0; k < KCH; k += 32) {
    frag8 a = *(const frag8*)(pA + k);
#pragma unroll
    for (int mt = 0; mt < 7; ++mt) {
      frag8 bb = *(const frag8*)(pB[mt] + k);
      acc[mt] = __builtin_amdgcn_mfma_f32_16x16x32_bf16(a, bb, acc[mt], 0, 0, 0);
    }
  }
  // C/D layout: col = lane&15 (m), row = (lane>>4)*4 + r (q)
#pragma unroll
  for (int mt = 0; mt < 7; ++mt) {
    int cm = mt * 16 + (lane & 15);
    if (cm < NM) {
#pragma unroll
      for (int r = 0; r < 4; ++r) {
        int cq = q0 + (lane >> 4) * 4 + r;
        if (cq < NQ)
          unsafeAtomicAdd(&dotv[((size_t)b * NQ + cq) * NM + cm], acc[mt][r]);
      }
    }
  }
}

// ---- combine all cost terms -> C (d_out) and transposed copy CT (ws) ----
__global__ __launch_bounds__(256) void combine_kernel(
    const float* __restrict__ dotv, const float* __restrict__ psum,
    const float* __restrict__ gsum, const float* __restrict__ probs,
    const int* __restrict__ labels, const float* __restrict__ pboxes,
    const float* __restrict__ gboxes, float* __restrict__ outC,
    float* __restrict__ ct) {
  int idx = blockIdx.x * 256 + threadIdx.x;
  if (idx >= NB * NQ * NM) return;
  int b = idx / (NQ * NM);
  int r = idx - b * (NQ * NM);
  int q = r / NM;
  int m = r - q * NM;
  float num = 2.f * dotv[idx];
  float den = psum[b * NQ + q] + gsum[b * NM + m];
  float cmask = 1.f - num / (den + 1e-6f);
  int lab = labels[b * NM + m];
  float cclass = -probs[((size_t)b * NQ + q) * NC + lab];
  const float* pb = pboxes + ((size_t)b * NQ + q) * 4;
  const float* gb = gboxes + ((size_t)b * NM + m) * 4;
  float p0 = pb[0], p1 = pb[1], p2 = pb[2], p3 = pb[3];
  float g0 = gb[0], g1 = gb[1], g2 = gb[2], g3 = gb[3];
  float cbbox = fabsf(p0 - g0) + fabsf(p1 - g1) + fabsf(p2 - g2) + fabsf(p3 - g3);
  float iw = fmaxf(fminf(p2, g2) - fmaxf(p0, g0), 0.f);
  float ih = fmaxf(fminf(p3, g3) - fmaxf(p1, g1), 0.f);
  float inter = iw * ih;
  float a1 = (p2 - p0) * (p3 - p1), a2 = (g2 - g0) * (g3 - g1);
  float uni = a1 + a2 - inter;
  float iou = inter / (uni + 1e-6f);
  float aw = fmaxf(fmaxf(p2, g2) - fminf(p0, g0), 0.f);
  float ah = fmaxf(fmaxf(p3, g3) - fminf(p1, g1), 0.f);
  float am = aw * ah;
  float giou = iou - (am - uni) / (am + 1e-6f);
  float C = cclass + 5.f * (cbbox - giou) + 2.f * cmask;
  outC[idx] = C;
  ct[((size_t)b * NM + m) * CTP + q] = C;   // transposed (pitch 305) for solver
}

// ---- LAPJV on cost.T [100 x 300], one wave per batch ----
// Rectangular: no column reduction; v=0 init. Augmenting-row-reduction x2
// (lap.cpp-faithful) loads v-penalties onto contested columns, then
// shortest-augmenting-path phases for remaining free rows. All hot state in
// registers (v,d,pred,scanned,colsol mirror); dual update once per phase;
// u implicit via tight matched edges. Exact optimum (duals stay feasible,
// matched edges tight); unique-optimum equivalence validated R2/R5.
extern __shared__ char hsmem[];
__global__ __launch_bounds__(64) void hungarian_kernel(
    const float* __restrict__ ct, float* __restrict__ out) {
  float* cost = (float*)hsmem;                   // 100*305*4 = 122000
  int* colsolL = (int*)(hsmem + 122000);         // 320*4
  int* rowsolL = (int*)(hsmem + 123280);         // 100*4
  int* predL   = (int*)(hsmem + 123680);         // 320*4
  int* freeL   = (int*)(hsmem + 124960);         // 128*4 -> end 125472
  const int b = blockIdx.x;
  const int lane = threadIdx.x;
  const float* a = ct + (size_t)b * NM * CTP;

  for (int i = lane; i < NM * CTP; i += 64) cost[i] = a[i];
  for (int i = lane; i < NM; i += 64) { rowsolL[i] = -1; freeL[i] = i; }
  float vv[5]; int cs[5];
#pragma unroll
  for (int w = 0; w < 5; ++w) { vv[w] = 0.f; cs[w] = -1; colsolL[lane + 64 * w] = -1; }
  __syncthreads();

  // ---- augmenting row reduction, two passes ----
  int nfree = NM;
  for (int pass = 0; pass < 2; ++pass) {
    int prv = nfree, k = 0, nf2 = 0, guard = 0;
    while (k < prv && guard < 1500) {
      ++guard;
      int i = freeL[k]; ++k;                      // uniform broadcast read
      // dual-min (min1,min2) over reduced costs of row i
      unsigned long long k1 = ~0ull, k2 = ~0ull;
#pragma unroll
      for (int w = 0; w < 5; ++w) {
        int j = lane + 64 * w;
        if (j < NQ) {
          unsigned long long key = packkey(cost[i * CTP + j] - vv[w], j);
          if (key < k1) { k2 = k1; k1 = key; }
          else if (key < k2) k2 = key;
        }
      }
#pragma unroll
      for (int off = 32; off > 0; off >>= 1) {
        unsigned long long o1 = __shfl_xor(k1, off, 64);
        unsigned long long o2 = __shfl_xor(k2, off, 64);
        unsigned long long n1 = (k1 < o1) ? k1 : o1;
        unsigned long long mx = (k1 < o1) ? o1 : k1;
        unsigned long long n2 = (k2 < o2) ? k2 : o2;
        if (mx < n2) n2 = mx;
        k1 = n1; k2 = n2;
      }
      int j1 = (int)(unsigned)k1;
      int j2 = (int)(unsigned)k2;
      float umin = unpackkey(k1), usub = unpackkey(k2);
      int i0; GET5I(cs, j1, i0);
      bool strict = (umin < usub);
      if (strict) {
        if (lane == (j1 & 63)) { int w1 = j1 >> 6; float dlt = usub - umin; SUB5F(vv, w1, dlt); }
      } else if (i0 >= 0) {
        j1 = j2;
        GET5I(cs, j2, i0);
      }
      if (lane == (j1 & 63)) { int w1 = j1 >> 6; SET5I(cs, w1, i); }
      if (lane == 0) { colsolL[j1] = i; rowsolL[i] = j1; }
      if (i0 >= 0) {
        if (lane == 0) rowsolL[i0] = -1;
        if (strict) { --k; if (lane == 0) freeL[k] = i0; }
        else { if (lane == 0) freeL[nf2] = i0; ++nf2; }
      }
      __builtin_amdgcn_wave_barrier();
    }
    while (k < prv) {                             // guard-tripped leftovers
      int lr = freeL[k]; ++k;
      if (lane == 0) freeL[nf2] = lr;
      ++nf2;
      __builtin_amdgcn_wave_barrier();
    }
    nfree = nf2;
  }

  // ---- shortest augmenting path for remaining free rows ----
  for (int f = 0; f < nfree; ++f) {
    int irow = freeL[f];
    float d[5]; int pr[5], sc[5];
#pragma unroll
    for (int w = 0; w < 5; ++w) {
      int j = lane + 64 * w;
      if (j < NQ) { d[w] = cost[irow * CTP + j] - vv[w]; sc[w] = 0; }
      else { d[w] = 1e30f; sc[w] = 1; }
      pr[w] = irow;
    }
    float mind = 0.f; int endj = -1;
    for (int pop = 0; pop < 310; ++pop) {
      unsigned long long k1 = ~0ull;
#pragma unroll
      for (int w = 0; w < 5; ++w)
        if (!sc[w]) { unsigned long long key = packkey(d[w], lane + 64 * w); if (key < k1) k1 = key; }
#pragma unroll
      for (int off = 32; off > 0; off >>= 1) {
        unsigned long long o = __shfl_xor(k1, off, 64);
        if (o < k1) k1 = o;
      }
      int j1 = (int)(unsigned)k1;
      mind = unpackkey(k1);
      int i0; GET5I(cs, j1, i0);
      if (i0 < 0) { endj = j1; break; }
      if (lane == (j1 & 63)) { int w1 = j1 >> 6; SET5I(sc, w1, 1); }
      float rv[5];
#pragma unroll
      for (int w = 0; w < 5; ++w) {
        int j = lane + 64 * w;
        rv[w] = (j < NQ) ? cost[i0 * CTP + j] : 0.f;
      }
      float cij1; GET5F(rv, j1, cij1);
      float vj1;  GET5F(vv, j1, vj1);
      float h = cij1 - vj1 - mind;                // = u[i0]
#pragma unroll
      for (int w = 0; w < 5; ++w) {
        int j = lane + 64 * w;
        if (j < NQ && !sc[w]) {
          float nd = rv[w] - vv[w] - h;
          if (nd < d[w]) { d[w] = nd; pr[w] = i0; }
        }
      }
    }
    // dual update for scanned columns
#pragma unroll
    for (int w = 0; w < 5; ++w) {
      int j = lane + 64 * w;
      if (j < NQ && sc[w]) vv[w] += d[w] - mind;
    }
    // augment along pred chain
#pragma unroll
    for (int w = 0; w < 5; ++w) predL[lane + 64 * w] = pr[w];
    __builtin_amdgcn_wave_barrier();
    if (lane == 0 && endj >= 0) {
      int j = endj;
      while (true) {
        int ii = predL[j];
        colsolL[j] = ii;
        int jn = rowsolL[ii];
        rowsolL[ii] = j;
        if (ii == irow) break;
        j = jn;
      }
    }
    __builtin_amdgcn_wave_barrier();
#pragma unroll
    for (int w = 0; w < 5; ++w) cs[w] = colsolL[lane + 64 * w];
    __builtin_amdgcn_wave_barrier();
  }

  // ---- emit sorted (pred, gt) pairs via ballot-prefix compaction ----
  float* po = out + NB * NQ * NM + b * NM;
  float* go = out + NB * NQ * NM + NB * NM + b * NM;
  int base = 0;
#pragma unroll
  for (int w = 0; w < 5; ++w) {
    int j = lane + 64 * w;
    bool valid = (j < NQ) && (cs[w] >= 0);
    unsigned long long mask = __ballot(valid);
    int pos = base + __popcll(mask & ((1ull << lane) - 1ull));
    if (valid) { po[pos] = (float)j; go[pos] = (float)cs[w]; }
    base += __popcll(mask);
  }
}

extern "C" void kernel_launch(void* const* d_in, const int* in_sizes, int n_in,
                              void* d_out, int out_size, void* d_ws, size_t ws_size,
                              hipStream_t stream) {
  const float* logits = (const float*)d_in[0];
  const float* pboxes = (const float*)d_in[1];
  const float* pmask  = (const float*)d_in[2];
  const int*   labels = (const int*)d_in[3];
  const float* gboxes = (const float*)d_in[4];
  const float* gmask  = (const float*)d_in[5];
  float* out = (float*)d_out;
  char* ws = (char*)d_ws;

  // ws layout (bytes)
  unsigned short* pm   = (unsigned short*)(ws + 0);          //  78,643,200
  unsigned short* gmb  = (unsigned short*)(ws + 78643200);   //  26,214,400
  float* psum  = (float*)(ws + 104857600);                   //       9,600
  float* gsum  = (float*)(ws + 104867200);                   //       3,200
  float* probs = (float*)(ws + 104870400);                   //     777,600
  float* dotv  = (float*)(ws + 105648000);                   //     960,000
  float* ct    = (float*)(ws + 106608000);                   //     976,000

  hipFuncSetAttribute(reinterpret_cast<const void*>(hungarian_kernel),
                      hipFuncAttributeMaxDynamicSharedMemorySize, 125472);

  hipMemsetAsync(dotv, 0, NB * NQ * NM * sizeof(float), stream);
  hipLaunchKernelGGL(prep_kernel, dim3(NB * NQ + NB * NM), dim3(256), 0, stream,
                     pmask, gmask, pm, gmb, psum, gsum);
  hipLaunchKernelGGL(softmax_kernel, dim3(600), dim3(256), 0, stream, logits, probs);
  hipLaunchKernelGGL(dot_kernel, dim3(8 * 19 * NKC), dim3(64), 0, stream, pm, gmb, dotv);
  hipLaunchKernelGGL(combine_kernel, dim3((NB * NQ * NM + 255) / 256), dim3(256), 0, stream,
                     dotv, psum, gsum, probs, labels, pboxes, gboxes, out, ct);
  hipLaunchKernelGGL(hungarian_kernel, dim3(NB), dim3(64), 125472, stream, ct, out);
}